// Round 1
// 19316.306 us; speedup vs baseline: 2.0151x; 2.0151x over previous
//
#include <hip/hip_runtime.h>
#include <math.h>

#define S_LEN 256
#define HDIM  768
#define G4    3072   // 4*HDIM
#define BATCH 64
#define MTOT  16384  // B*S

__device__ __forceinline__ float sigmoidf_(float x) { return 1.0f / (1.0f + expf(-x)); }

// ---------- pack: out[k][hc*4+g] = in[k][g*768+hc]  (gate-interleaved cols) ----------
__global__ __launch_bounds__(256) void pack_w_kernel(const float* __restrict__ in, float* __restrict__ out) {
    int idx = blockIdx.x * 256 + threadIdx.x;   // < 768*3072
    int k = idx / G4;
    int n = idx - k * G4;
    int hc = n >> 2, g = n & 3;
    out[idx] = in[k * G4 + g * HDIM + hc];
}

// ---------- embedding gather, time-major rows: emb[m'=t*64+b][:] = table[ids[b*256+t]][:] ----------
__global__ __launch_bounds__(192) void embed_kernel(const int* __restrict__ ids, const float* __restrict__ table,
                                                    float* __restrict__ emb) {
    int row = blockIdx.x;             // m' = t*64 + b
    int t = row >> 6, b = row & 63;
    int id = ids[b * S_LEN + t];
    const float4* src = (const float4*)(table + (long long)id * HDIM);
    float4* dst = (float4*)(emb + (long long)row * HDIM);
    dst[threadIdx.x] = src[threadIdx.x];
}

// ---------- entity transpose: entT[t*64+b] = ent[b*256+t] ----------
__global__ __launch_bounds__(64) void entT_kernel(const int* __restrict__ ent, int* __restrict__ entT) {
    int t = blockIdx.x, b = threadIdx.x;
    entT[t * 64 + b] = ent[b * S_LEN + t];
}

// ---------- big GEMM producing C^T: CT[n][m] = sum_k A[m][k]*Bp[k][n] + bias(n) ----------
// AT=0: A is [M][768] row-major.  AT=1: A is A^T = [768][M] row-major (M=16384).
template<int AT>
__global__ __launch_bounds__(256) void gemm_xw_kernel(const float* __restrict__ A, const float* __restrict__ Bp,
                                                      const float* __restrict__ bias, float* __restrict__ CT) {
    __shared__ float As[16][132];
    __shared__ float Bs[16][132];
    int tid = threadIdx.x;
    int tx = tid & 15, ty = tid >> 4;
    int m0 = blockIdx.x * 128;
    int n0 = blockIdx.y * 128;
    float acc[8][8];
#pragma unroll
    for (int i = 0; i < 8; ++i)
#pragma unroll
        for (int j = 0; j < 8; ++j) acc[i][j] = 0.f;

    int ar = tid >> 2;              // 0..63   (AT=0 path)
    int ak = (tid & 3) << 2;        // 0,4,8,12
    int kr = tid >> 5;              // 0..7    (AT=1 path)
    int mc = (tid & 31) << 2;       // 0..124
    int bk = tid >> 5;              // 0..7
    int bn = (tid & 31) << 2;       // 0..124

    for (int kc = 0; kc < HDIM; kc += 16) {
        if (AT == 0) {
            float4 a0 = *(const float4*)&A[(long long)(m0 + ar) * HDIM + kc + ak];
            float4 a1 = *(const float4*)&A[(long long)(m0 + ar + 64) * HDIM + kc + ak];
            As[ak + 0][ar] = a0.x; As[ak + 1][ar] = a0.y; As[ak + 2][ar] = a0.z; As[ak + 3][ar] = a0.w;
            As[ak + 0][ar + 64] = a1.x; As[ak + 1][ar + 64] = a1.y; As[ak + 2][ar + 64] = a1.z; As[ak + 3][ar + 64] = a1.w;
        } else {
            float4 t0 = *(const float4*)&A[(long long)(kc + kr) * MTOT + m0 + mc];
            float4 t1 = *(const float4*)&A[(long long)(kc + kr + 8) * MTOT + m0 + mc];
            *(float4*)&As[kr][mc] = t0;
            *(float4*)&As[kr + 8][mc] = t1;
        }
        float4 b0v = *(const float4*)&Bp[(long long)(kc + bk) * G4 + n0 + bn];
        float4 b1v = *(const float4*)&Bp[(long long)(kc + bk + 8) * G4 + n0 + bn];
        *(float4*)&Bs[bk][bn] = b0v;
        *(float4*)&Bs[bk + 8][bn] = b1v;
        __syncthreads();
#pragma unroll
        for (int k = 0; k < 16; ++k) {
            float a[8], b[8];
            *(float4*)&a[0] = *(const float4*)&As[k][ty * 8];
            *(float4*)&a[4] = *(const float4*)&As[k][ty * 8 + 4];
            *(float4*)&b[0] = *(const float4*)&Bs[k][tx * 8];
            *(float4*)&b[4] = *(const float4*)&Bs[k][tx * 8 + 4];
#pragma unroll
            for (int i = 0; i < 8; ++i)
#pragma unroll
                for (int j = 0; j < 8; ++j)
                    acc[i][j] = fmaf(a[i], b[j], acc[i][j]);
        }
        __syncthreads();
    }
    // epilogue: CT[n][m] with bias per packed col n (n = hc*4+g -> bias[g*768+hc])
#pragma unroll
    for (int j = 0; j < 8; ++j) {
        int n = n0 + tx * 8 + j;
        float bb = bias[(n & 3) * HDIM + (n >> 2)];
        float4 v0, v1;
        v0.x = acc[0][j] + bb; v0.y = acc[1][j] + bb; v0.z = acc[2][j] + bb; v0.w = acc[3][j] + bb;
        v1.x = acc[4][j] + bb; v1.y = acc[5][j] + bb; v1.z = acc[6][j] + bb; v1.w = acc[7][j] + bb;
        *(float4*)&CT[(long long)n * MTOT + m0 + ty * 8] = v0;
        *(float4*)&CT[(long long)n * MTOT + m0 + ty * 8 + 4] = v1;
    }
}

// ---------- recurrent LSTM layer (cooperative, persistent Wh in LDS) ----------
// grid 256 blocks x 256 thr. Block owns 3 hc (12 packed cols). Wh slice in LDS (read once).
// XGPT: [3072][16384] gate pre-activations (x@Wx+b), [col][m'=t*64+b].
// outT: [768][16384] h outputs, [hc][m'].
// h4:   double-buffered global h, dword layout [buf][k4][b][j] (j = k&3), i.e. float4[buf][192][64].
//
// Sync design (replaces cg::grid.sync + __threadfence, which cost ~60us/step in
// L2 wb/inv + sleepy spin):
//   release:  h published via agent-scope relaxed atomic stores (sc1 write-through to LLC,
//             no L2 writeback needed) + bare s_waitcnt vmcnt(0) + block barrier.
//   arrive:   one relaxed agent atomicAdd per block on a monotonic counter.
//   wait:     tid0 spins on relaxed agent load (LLC read each poll, no cache maintenance).
//   acquire:  one agent-scope acquire fence (buffer_inv) per step, so the PLAIN float4
//             h reads in the hot loop fetch fresh lines from LLC (and same-XCD L2 can
//             legally absorb the 32-block read redundancy within a step).
// Buffer invariant unchanged: reads of buf[t&1] complete before barrier t; writes to
// buf[t&1] (= buf[(t+2)&1]) happen only after barrier t has been passed by all blocks.
#define WPAD 772
__global__ __launch_bounds__(256, 1) void lstm_kernel(const float* __restrict__ XGPT, const float* __restrict__ WhP,
                                                      float* __restrict__ outT, float* __restrict__ h4,
                                                      int* __restrict__ bar) {
    __shared__ float WhS[12 * WPAD];
    __shared__ float gb[3 * 64 * 4];  // [j][b][cg]
    int tid = threadIdx.x;
    int blk = blockIdx.x;
    int colbase = blk * 12;

    // one-time: stage Wh slice into LDS. WhS[cc][k] = WhP[k][colbase+cc]
    for (int i = tid; i < 12 * HDIM; i += 256) {
        int k = i / 12;
        int cc = i - k * 12;
        WhS[cc * WPAD + k] = WhP[(long long)k * G4 + colbase + cc];
    }
    __syncthreads();

    int b16 = tid & 15;
    int cg_ = (tid >> 4) & 3;
    int bhi = tid >> 6;
    int b = bhi * 16 + b16;
    const float* W0 = &WhS[(0 * 4 + cg_) * WPAD];
    const float* W1 = &WhS[(1 * 4 + cg_) * WPAD];
    const float* W2 = &WhS[(2 * 4 + cg_) * WPAD];
    const float* xg0 = &XGPT[(long long)(colbase + 0 * 4 + cg_) * MTOT];
    const float* xg1 = &XGPT[(long long)(colbase + 1 * 4 + cg_) * MTOT];
    const float* xg2 = &XGPT[(long long)(colbase + 2 * 4 + cg_) * MTOT];

    // combine-role mapping (threads 0..191): (cb, cj) owns cell state of (b=cb, hc=blk*3+cj)
    int cb = tid & 63, cj = tid >> 6;
    int hc = blk * 3 + cj;
    int wk4 = hc >> 2, wj = hc & 3;          // writer position in h4
    float cstate = 0.f;

    for (int t = 0; t < S_LEN; ++t) {
        const float4* hp = ((const float4*)h4) + (t & 1) * (192 * 64) + b;
        float a0 = 0.f, a1 = 0.f, a2 = 0.f;
#pragma unroll 4
        for (int k4 = 0; k4 < 192; ++k4) {
            float4 hv = hp[k4 * 64];
            float4 w0 = *(const float4*)&W0[k4 * 4];
            float4 w1 = *(const float4*)&W1[k4 * 4];
            float4 w2 = *(const float4*)&W2[k4 * 4];
            a0 = fmaf(hv.x, w0.x, a0); a0 = fmaf(hv.y, w0.y, a0); a0 = fmaf(hv.z, w0.z, a0); a0 = fmaf(hv.w, w0.w, a0);
            a1 = fmaf(hv.x, w1.x, a1); a1 = fmaf(hv.y, w1.y, a1); a1 = fmaf(hv.z, w1.z, a1); a1 = fmaf(hv.w, w1.w, a1);
            a2 = fmaf(hv.x, w2.x, a2); a2 = fmaf(hv.y, w2.y, a2); a2 = fmaf(hv.z, w2.z, a2); a2 = fmaf(hv.w, w2.w, a2);
        }
        int mi = t * 64 + b;
        a0 += xg0[mi];
        a1 += xg1[mi];
        a2 += xg2[mi];
        gb[0 * 256 + b * 4 + cg_] = a0;
        gb[1 * 256 + b * 4 + cg_] = a1;
        gb[2 * 256 + b * 4 + cg_] = a2;
        __syncthreads();
        if (tid < 192) {
            float4 g4v = *(const float4*)&gb[cj * 256 + cb * 4];
            float ig = sigmoidf_(g4v.x);
            float fg = sigmoidf_(g4v.y);
            float gg = tanhf(g4v.z);
            float og = sigmoidf_(g4v.w);
            cstate = fmaf(fg, cstate, ig * gg);
            float h = og * tanhf(cstate);
            outT[(long long)hc * MTOT + t * 64 + cb] = h;
            // publish h at the coherent point (write-through, no L2 flush needed)
            __hip_atomic_store(&h4[((t + 1) & 1) * (192 * 64 * 4) + wk4 * 256 + cb * 4 + wj], h,
                               __ATOMIC_RELAXED, __HIP_MEMORY_SCOPE_AGENT);
        }
        // release: all this wave's h stores ack'd at the coherent point
        asm volatile("s_waitcnt vmcnt(0)" ::: "memory");
        __syncthreads();   // all waves of this block have published
        if (tid == 0) {
            __hip_atomic_fetch_add(bar, 1, __ATOMIC_RELAXED, __HIP_MEMORY_SCOPE_AGENT);
            int target = (t + 1) << 8;   // 256 blocks per step, monotonic counter
            while (__hip_atomic_load(bar, __ATOMIC_RELAXED, __HIP_MEMORY_SCOPE_AGENT) < target) { }
        }
        // acquire: invalidate L1/L2 so next step's plain h loads read fresh LLC data
        __builtin_amdgcn_fence(__ATOMIC_ACQUIRE, "agent");
        __syncthreads();
    }
}

// ---------- pool GEMM (split-K by hc + atomics): pool[64][768] += A @ W ----------
// A logical [64 b][k=t*768+hc], stored as out1T[hc][t*64+b]. W: poolW[k][768].
__global__ __launch_bounds__(256) void pool_gemm_kernel(const float* __restrict__ AT, const float* __restrict__ W,
                                                        float* __restrict__ pool) {
    __shared__ float As2[64 * 64];
    __shared__ float Ws[64][132];
    int tid = threadIdx.x;
    int tx = tid & 15, ty = tid >> 4;
    int n0 = blockIdx.x * 128;
    int hcbase = blockIdx.y * 12;
    float acc[4][8];
#pragma unroll
    for (int i = 0; i < 4; ++i)
#pragma unroll
        for (int j = 0; j < 8; ++j) acc[i][j] = 0.f;

    for (int hh = 0; hh < 12; ++hh) {
        int hc = hcbase + hh;
        for (int tc = 0; tc < 4; ++tc) {
            int t0 = tc * 64;
            // stage A chunk: As2[tr][b] = AT[hc][(t0+tr)*64 + b]
            const float4* src = (const float4*)&AT[(long long)hc * MTOT + t0 * 64];
            float4* dst = (float4*)As2;
            for (int it = 0; it < 4; ++it) dst[tid + it * 256] = src[tid + it * 256];
            // stage W chunk: Ws[tr][nc] = W[((t0+tr)*768+hc)][n0+nc]
            for (int l = tid; l < 64 * 32; l += 256) {
                int tr = l >> 5, nc = (l & 31) << 2;
                *(float4*)&Ws[tr][nc] = *(const float4*)&W[(long long)((t0 + tr) * HDIM + hc) * HDIM + n0 + nc];
            }
            __syncthreads();
            for (int k = 0; k < 64; ++k) {
                float wv[8];
                *(float4*)&wv[0] = *(const float4*)&Ws[k][tx * 8];
                *(float4*)&wv[4] = *(const float4*)&Ws[k][tx * 8 + 4];
#pragma unroll
                for (int i = 0; i < 4; ++i) {
                    float av = As2[k * 64 + ty * 4 + i];
#pragma unroll
                    for (int j = 0; j < 8; ++j) acc[i][j] = fmaf(av, wv[j], acc[i][j]);
                }
            }
            __syncthreads();
        }
    }
#pragma unroll
    for (int i = 0; i < 4; ++i)
#pragma unroll
        for (int j = 0; j < 8; ++j)
            atomicAdd(&pool[(ty * 4 + i) * HDIM + n0 + tx * 8 + j], acc[i][j]);
}

// ---------- entity max + pooled = max(ent_max, pool + pool_b) ----------
// out1T: [hc][t*64+b]; entT: [t*64+b]. grid 768 (h), 64 thr (b).
__global__ __launch_bounds__(64) void entpool_kernel(const float* __restrict__ out1T, const int* __restrict__ entT,
                                                     const float* __restrict__ pool, const float* __restrict__ pool_b,
                                                     float* __restrict__ pooled) {
    int h = blockIdx.x, b = threadIdx.x;
    const float* row = out1T + (long long)h * MTOT;
    float best = -INFINITY;
    for (int t = 0; t < S_LEN; ++t) {
        int m = t * 64 + b;
        float v = (entT[m] == 1) ? row[m] : 0.f;
        best = fmaxf(best, v);
    }
    float p = pool[b * HDIM + h] + pool_b[h];
    pooled[b * HDIM + h] = fmaxf(best, p);
}

// ---------- logits[64][2] = pooled @ lin_W + lin_b ----------
__global__ __launch_bounds__(256) void logits_kernel(const float* __restrict__ pooled, const float* __restrict__ linW,
                                                     const float* __restrict__ linb, float* __restrict__ outp) {
    __shared__ float r0[256], r1[256];
    int b = blockIdx.x, tid = threadIdx.x;
    float a0 = 0.f, a1 = 0.f;
    for (int h = tid; h < HDIM; h += 256) {
        float p = pooled[b * HDIM + h];
        a0 = fmaf(p, linW[h * 2 + 0], a0);
        a1 = fmaf(p, linW[h * 2 + 1], a1);
    }
    r0[tid] = a0; r1[tid] = a1;
    __syncthreads();
    for (int s = 128; s > 0; s >>= 1) {
        if (tid < s) { r0[tid] += r0[tid + s]; r1[tid] += r1[tid + s]; }
        __syncthreads();
    }
    if (tid == 0) {
        outp[b * 2 + 0] = r0[0] + linb[0];
        outp[b * 2 + 1] = r1[0] + linb[1];
    }
}

extern "C" void kernel_launch(void* const* d_in, const int* in_sizes, int n_in,
                              void* d_out, int out_size, void* d_ws, size_t ws_size,
                              hipStream_t stream) {
    const int*   input_ids = (const int*)d_in[0];
    const int*   entity    = (const int*)d_in[4];
    const float* table     = (const float*)d_in[5];
    const float* Wx0 = (const float*)d_in[6];
    const float* Wh0 = (const float*)d_in[7];
    const float* b0  = (const float*)d_in[8];
    const float* Wx1 = (const float*)d_in[9];
    const float* Wh1 = (const float*)d_in[10];
    const float* b1  = (const float*)d_in[11];
    const float* poolW = (const float*)d_in[12];
    const float* poolb = (const float*)d_in[13];
    const float* linW  = (const float*)d_in[14];
    const float* linb  = (const float*)d_in[15];

    // workspace layout (floats), total ~325 MiB
    float* ws    = (float*)d_ws;
    float* WxP0  = ws;                        // 2359296
    float* WhP0  = WxP0 + 2359296;
    float* WxP1  = WhP0 + 2359296;
    float* WhP1  = WxP1 + 2359296;
    float* embA  = WhP1 + 2359296;            // [16384][768] time-major; reused as out1T
    float* XGPT  = embA + 12582912;           // [3072][16384]
    float* out0T = XGPT + 50331648;           // [768][16384]
    float* h4    = out0T + 12582912;          // 2 x float4[192][64] = 98304 floats
    float* pool  = h4 + 98304;                // [64][768]
    float* pooled = pool + 49152;             // [64][768]
    int*   entT  = (int*)(pooled + 49152);    // 16384 ints
    int*   bar   = entT + 16384;              // grid barrier counter (monotonic per launch)
    float* out1T = embA;

    pack_w_kernel<<<9216, 256, 0, stream>>>(Wx0, WxP0);
    pack_w_kernel<<<9216, 256, 0, stream>>>(Wh0, WhP0);
    pack_w_kernel<<<9216, 256, 0, stream>>>(Wx1, WxP1);
    pack_w_kernel<<<9216, 256, 0, stream>>>(Wh1, WhP1);
    embed_kernel<<<16384, 192, 0, stream>>>(input_ids, table, embA);
    entT_kernel<<<256, 64, 0, stream>>>(entity, entT);

    gemm_xw_kernel<0><<<dim3(128, 24), 256, 0, stream>>>(embA, WxP0, b0, XGPT);
    hipMemsetAsync(h4, 0, 49152 * sizeof(float), stream);   // zero read-buffer for t=0
    hipMemsetAsync(bar, 0, sizeof(int), stream);
    {
        const float* a0 = XGPT; const float* a1 = WhP0; float* a2 = out0T; float* a3 = h4; int* a4 = bar;
        void* args[] = {&a0, &a1, &a2, &a3, &a4};
        hipLaunchCooperativeKernel((const void*)lstm_kernel, dim3(256), dim3(256), args, 0, stream);
    }
    gemm_xw_kernel<1><<<dim3(128, 24), 256, 0, stream>>>(out0T, WxP1, b1, XGPT);
    hipMemsetAsync(h4, 0, 49152 * sizeof(float), stream);
    hipMemsetAsync(bar, 0, sizeof(int), stream);
    {
        const float* a0 = XGPT; const float* a1 = WhP1; float* a2 = out1T; float* a3 = h4; int* a4 = bar;
        void* args[] = {&a0, &a1, &a2, &a3, &a4};
        hipLaunchCooperativeKernel((const void*)lstm_kernel, dim3(256), dim3(256), args, 0, stream);
    }

    hipMemsetAsync(pool, 0, 49152 * sizeof(float), stream);
    pool_gemm_kernel<<<dim3(6, 64), 256, 0, stream>>>(out1T, poolW, pool);
    entpool_kernel<<<768, 64, 0, stream>>>(out1T, entT, pool, poolb, pooled);
    logits_kernel<<<64, 256, 0, stream>>>(pooled, linW, linb, (float*)d_out);
}